// Round 2
// baseline (946.533 us; speedup 1.0000x reference)
//
#include <hip/hip_runtime.h>

#define D 128
#define GNUM 512

// ---------------- zero fill ----------------
__global__ void zero_kernel(float* __restrict__ p, int n4) {
  int i = blockIdx.x * blockDim.x + threadIdx.x;
  if (i < n4) ((float4*)p)[i] = make_float4(0.f, 0.f, 0.f, 0.f);
}

// ---------------- edge scatter-add: agg[dst] += feat[src] ----------------
__global__ void scatter_kernel(const float* __restrict__ feat,
                               const int* __restrict__ ei,
                               float* __restrict__ agg, int nE) {
  long long tid = (long long)blockIdx.x * blockDim.x + threadIdx.x;
  if (tid >= (long long)nE * D) return;
  int e = (int)(tid >> 7);
  int c = (int)(tid & 127);
  int s = ei[e];
  int d = ei[nE + e];
  atomicAdd(agg + (size_t)d * D + c, feat[(size_t)s * D + c]);
}

// ---------------- GEMM: C[n,128] = f(A)[n,128] @ W[128,128] + b ----------
// MODE 0: f(A) = A + X (per-element); no output activation   (GIN linear1)
// MODE 1: f(A) = relu(A*scale[k] + shift[k]) (BN+ReLU on load); relu output
// WRITEC: write C rows. POOL: atomically pool relu output into pooled[g][..]
template <int MODE, int WRITEC, int POOL>
__global__ __launch_bounds__(256) void gemm_kernel(
    const float* __restrict__ A,
    const float* __restrict__ X,   // MODE0: x/h_prev ; MODE1: scaleshift[256]
    const float* __restrict__ W,
    const float* __restrict__ bias,
    float* __restrict__ C,
    const int* __restrict__ batch,
    float* __restrict__ pooled, int poolbase, int n) {
  __shared__ float Alds[16][132];  // [k][r], padded stride
  __shared__ float Wlds[16][128];  // [k][j]
  const int t = threadIdx.x;
  const int row0 = blockIdx.x * 128;
  const int tr = t >> 4, tc = t & 15;

  float acc[8][8];
#pragma unroll
  for (int i = 0; i < 8; i++)
#pragma unroll
    for (int j = 0; j < 8; j++) acc[i][j] = 0.f;

  for (int k0 = 0; k0 < D; k0 += 16) {
    // stage A chunk (128 rows x 16 k), transposed into LDS
#pragma unroll
    for (int rep = 0; rep < 2; rep++) {
      int idx = t + rep * 256;       // 0..511
      int r = idx >> 2, kq = idx & 3;
      int gr = row0 + r;
      float4 v = make_float4(0.f, 0.f, 0.f, 0.f);
      if (gr < n) {
        v = *(const float4*)(A + (size_t)gr * D + k0 + kq * 4);
        if (MODE == 0) {
          float4 xv = *(const float4*)(X + (size_t)gr * D + k0 + kq * 4);
          v.x += xv.x; v.y += xv.y; v.z += xv.z; v.w += xv.w;
        } else {
          int kk = k0 + kq * 4;
          v.x = fmaxf(0.f, fmaf(v.x, X[kk + 0], X[128 + kk + 0]));
          v.y = fmaxf(0.f, fmaf(v.y, X[kk + 1], X[128 + kk + 1]));
          v.z = fmaxf(0.f, fmaf(v.z, X[kk + 2], X[128 + kk + 2]));
          v.w = fmaxf(0.f, fmaf(v.w, X[kk + 3], X[128 + kk + 3]));
        }
      }
      Alds[kq * 4 + 0][r] = v.x;
      Alds[kq * 4 + 1][r] = v.y;
      Alds[kq * 4 + 2][r] = v.z;
      Alds[kq * 4 + 3][r] = v.w;
    }
    // stage W chunk (16 k x 128 j)
#pragma unroll
    for (int rep = 0; rep < 2; rep++) {
      int idx = t + rep * 256;
      int kr = idx >> 5, jq = idx & 31;
      *(float4*)(&Wlds[kr][jq * 4]) =
          *(const float4*)(W + (size_t)(k0 + kr) * D + jq * 4);
    }
    __syncthreads();
#pragma unroll
    for (int k = 0; k < 16; k++) {
      float a[8], w[8];
      *(float4*)(a)     = *(const float4*)(&Alds[k][tr * 8]);
      *(float4*)(a + 4) = *(const float4*)(&Alds[k][tr * 8 + 4]);
      *(float4*)(w)     = *(const float4*)(&Wlds[k][tc * 8]);
      *(float4*)(w + 4) = *(const float4*)(&Wlds[k][tc * 8 + 4]);
#pragma unroll
      for (int i = 0; i < 8; i++)
#pragma unroll
        for (int j = 0; j < 8; j++) acc[i][j] = fmaf(a[i], w[j], acc[i][j]);
    }
    __syncthreads();
  }

  // ---------------- epilogue ----------------
  if constexpr (POOL == 0) {
#pragma unroll
    for (int i = 0; i < 8; i++) {
      int gr = row0 + tr * 8 + i;
      if (gr < n) {
#pragma unroll
        for (int jq = 0; jq < 2; jq++) {
          int col = tc * 8 + jq * 4;
          float4 o;
          o.x = acc[i][jq * 4 + 0] + bias[col + 0];
          o.y = acc[i][jq * 4 + 1] + bias[col + 1];
          o.z = acc[i][jq * 4 + 2] + bias[col + 2];
          o.w = acc[i][jq * 4 + 3] + bias[col + 3];
          if (MODE == 1) {
            o.x = fmaxf(0.f, o.x); o.y = fmaxf(0.f, o.y);
            o.z = fmaxf(0.f, o.z); o.w = fmaxf(0.f, o.w);
          }
          *(float4*)(C + (size_t)gr * D + col) = o;
        }
      }
    }
  } else {
    // MODE==1 here: relu output, pool sum+max per graph.
    const int r0g = row0 + tr * 8;
    int uniform = 0, gu = 0;
    if (r0g + 7 < n) {
      int b0 = batch[r0g], b7 = batch[r0g + 7];
      if (b0 == b7) { uniform = 1; gu = b0; }
    }
#pragma unroll
    for (int jq = 0; jq < 2; jq++) {
      const int col = tc * 8 + jq * 4;
      const float b0 = bias[col], b1 = bias[col + 1];
      const float b2 = bias[col + 2], b3 = bias[col + 3];
      float s0 = 0.f, s1 = 0.f, s2 = 0.f, s3 = 0.f;
      float m0 = 0.f, m1 = 0.f, m2 = 0.f, m3 = 0.f;
#pragma unroll
      for (int i = 0; i < 8; i++) {
        int gr = r0g + i;
        if (gr < n) {
          float o0 = fmaxf(0.f, acc[i][jq * 4 + 0] + b0);
          float o1 = fmaxf(0.f, acc[i][jq * 4 + 1] + b1);
          float o2 = fmaxf(0.f, acc[i][jq * 4 + 2] + b2);
          float o3 = fmaxf(0.f, acc[i][jq * 4 + 3] + b3);
          if constexpr (WRITEC) {
            *(float4*)(C + (size_t)gr * D + col) = make_float4(o0, o1, o2, o3);
          }
          if (uniform) {
            s0 += o0; s1 += o1; s2 += o2; s3 += o3;
            m0 = fmaxf(m0, o0); m1 = fmaxf(m1, o1);
            m2 = fmaxf(m2, o2); m3 = fmaxf(m3, o3);
          } else {
            int g = batch[gr];
            float* ps = pooled + (size_t)g * 512 + poolbase + col;
            atomicAdd(ps + 0, o0); atomicAdd(ps + 1, o1);
            atomicAdd(ps + 2, o2); atomicAdd(ps + 3, o3);
            int* pm = (int*)(pooled + (size_t)g * 512 + poolbase + 256 + col);
            atomicMax(pm + 0, __float_as_int(o0));
            atomicMax(pm + 1, __float_as_int(o1));
            atomicMax(pm + 2, __float_as_int(o2));
            atomicMax(pm + 3, __float_as_int(o3));
          }
        }
      }
      if (uniform) {
        float* ps = pooled + (size_t)gu * 512 + poolbase + col;
        atomicAdd(ps + 0, s0); atomicAdd(ps + 1, s1);
        atomicAdd(ps + 2, s2); atomicAdd(ps + 3, s3);
        int* pm = (int*)(pooled + (size_t)gu * 512 + poolbase + 256 + col);
        atomicMax(pm + 0, __float_as_int(m0));
        atomicMax(pm + 1, __float_as_int(m1));
        atomicMax(pm + 2, __float_as_int(m2));
        atomicMax(pm + 3, __float_as_int(m3));
      }
    }
  }
}

// ------------- per-column sum / sumsq over tmp[n,128] --------------------
__global__ void colreduce_kernel(const float* __restrict__ tmp,
                                 float* __restrict__ colsum, int n) {
  int c = threadIdx.x;  // 128 threads
  int rows_per_block = (n + gridDim.x - 1) / gridDim.x;
  int r0 = blockIdx.x * rows_per_block;
  int r1 = min(r0 + rows_per_block, n);
  float s = 0.f, sq = 0.f;
  for (int r = r0; r < r1; r++) {
    float v = tmp[(size_t)r * D + c];
    s += v;
    sq = fmaf(v, v, sq);
  }
  atomicAdd(colsum + c, s);
  atomicAdd(colsum + 128 + c, sq);
}

// ------------- BN stats -> scale/shift -----------------------------------
__global__ void bnstats_kernel(const float* __restrict__ colsum,
                               const float* __restrict__ g,
                               const float* __restrict__ be,
                               float* __restrict__ ss, int n) {
  int c = threadIdx.x;  // 128
  float inv_n = 1.0f / (float)n;
  float mean = colsum[c] * inv_n;
  float var = colsum[128 + c] * inv_n - mean * mean;
  float scale = g[c] * rsqrtf(var + 1e-5f);
  ss[c] = scale;
  ss[128 + c] = be[c] - mean * scale;
}

// ------------- readout lin1: out1[G,512] = relu(pooled @ W + b) ----------
__global__ __launch_bounds__(512) void lin1_kernel(
    const float* __restrict__ pooled, const float* __restrict__ W,
    const float* __restrict__ b, float* __restrict__ out1) {
  __shared__ float prow[8][512];
  int j = threadIdx.x;
  int g0 = blockIdx.x * 8;
#pragma unroll
  for (int rep = 0; rep < 2; rep++) {
    int idx = threadIdx.x + rep * 512;  // 0..1023 float4 chunks
    int r = idx >> 7;
    int q = idx & 127;
    *(float4*)(&prow[r][q * 4]) =
        *(const float4*)(pooled + (size_t)(g0 + r) * 512 + q * 4);
  }
  __syncthreads();
  float acc[8];
#pragma unroll
  for (int r = 0; r < 8; r++) acc[r] = 0.f;
  for (int k = 0; k < 512; k++) {
    float w = W[(size_t)k * 512 + j];
#pragma unroll
    for (int r = 0; r < 8; r++) acc[r] = fmaf(prow[r][k], w, acc[r]);
  }
  float bj = b[j];
#pragma unroll
  for (int r = 0; r < 8; r++)
    out1[(size_t)(g0 + r) * 512 + j] = fmaxf(0.f, acc[r] + bj);
}

// ------------- readout lin2 + sigmoid ------------------------------------
__global__ void lin2_kernel(const float* __restrict__ out1,
                            const float* __restrict__ W,
                            const float* __restrict__ b,
                            float* __restrict__ out) {
  int g = blockIdx.x;
  int lane = threadIdx.x;  // 64
  float s = 0.f;
  for (int k = lane; k < 512; k += 64)
    s = fmaf(out1[(size_t)g * 512 + k], W[k], s);
#pragma unroll
  for (int off = 32; off > 0; off >>= 1) s += __shfl_down(s, off);
  if (lane == 0) {
    float h = s + b[0];
    out[g] = 1.0f / (1.0f + expf(-h));
    out[GNUM + g] = h;
  }
}

extern "C" void kernel_launch(void* const* d_in, const int* in_sizes, int n_in,
                              void* d_out, int out_size, void* d_ws,
                              size_t ws_size, hipStream_t stream) {
  const float* x = (const float*)d_in[0];
  const int* ei = (const int*)d_in[1];      // harness passes integer as int32
  const int* batch = (const int*)d_in[2];
  const float* c1_W1 = (const float*)d_in[3];
  const float* c1_b1 = (const float*)d_in[4];
  const float* c1_g  = (const float*)d_in[5];
  const float* c1_be = (const float*)d_in[6];
  const float* c1_W2 = (const float*)d_in[7];
  const float* c1_b2 = (const float*)d_in[8];
  const float* c2_W1 = (const float*)d_in[9];
  const float* c2_b1 = (const float*)d_in[10];
  const float* c2_g  = (const float*)d_in[11];
  const float* c2_be = (const float*)d_in[12];
  const float* c2_W2 = (const float*)d_in[13];
  const float* c2_b2 = (const float*)d_in[14];
  const float* lin1_W = (const float*)d_in[15];
  const float* lin1_b = (const float*)d_in[16];
  const float* lin2_W = (const float*)d_in[17];
  const float* lin2_b = (const float*)d_in[18];

  const int n = in_sizes[0] / D;        // 50000
  const int nE = in_sizes[1] / 2;       // 600000

  float* ws = (float*)d_ws;
  float* aggtmp = ws;                       // n*D
  float* colsum = ws + (size_t)n * D;       // 256 (sum128 + sq128)
  float* ssbuf  = colsum + 256;             // 256 (scale128 + shift128)
  float* h1 = ssbuf + 256;                  // n*D
  float* pooled = h1 + (size_t)n * D;       // GNUM*512
  float* out1b  = pooled + (size_t)GNUM * 512;  // GNUM*512
  // total: 2*n*D + 512 + 2*GNUM*512 floats ~= 53.3 MB

  const int gemm_grid = (n + 127) / 128;
  const long long scatter_threads = (long long)nE * D;
  const int scatter_grid = (int)((scatter_threads + 255) / 256);
  const int zero1_n4 = (n * D + 256) / 4;   // aggtmp + colsum contiguous
  const int zeroP_n4 = (GNUM * 512) / 4;

  // ---------------- layer 1 ----------------
  zero_kernel<<<(zero1_n4 + 255) / 256, 256, 0, stream>>>(aggtmp, zero1_n4);
  zero_kernel<<<(zeroP_n4 + 255) / 256, 256, 0, stream>>>(pooled, zeroP_n4);
  scatter_kernel<<<scatter_grid, 256, 0, stream>>>(x, ei, aggtmp, nE);
  gemm_kernel<0, 1, 0><<<gemm_grid, 256, 0, stream>>>(
      aggtmp, x, c1_W1, c1_b1, aggtmp, nullptr, nullptr, 0, n);
  colreduce_kernel<<<256, 128, 0, stream>>>(aggtmp, colsum, n);
  bnstats_kernel<<<1, 128, 0, stream>>>(colsum, c1_g, c1_be, ssbuf, n);
  gemm_kernel<1, 1, 1><<<gemm_grid, 256, 0, stream>>>(
      aggtmp, ssbuf, c1_W2, c1_b2, h1, batch, pooled, 0, n);

  // ---------------- layer 2 ----------------
  zero_kernel<<<(zero1_n4 + 255) / 256, 256, 0, stream>>>(aggtmp, zero1_n4);
  scatter_kernel<<<scatter_grid, 256, 0, stream>>>(h1, ei, aggtmp, nE);
  gemm_kernel<0, 1, 0><<<gemm_grid, 256, 0, stream>>>(
      aggtmp, h1, c2_W1, c2_b1, aggtmp, nullptr, nullptr, 0, n);
  colreduce_kernel<<<256, 128, 0, stream>>>(aggtmp, colsum, n);
  bnstats_kernel<<<1, 128, 0, stream>>>(colsum, c2_g, c2_be, ssbuf, n);
  gemm_kernel<1, 0, 1><<<gemm_grid, 256, 0, stream>>>(
      aggtmp, ssbuf, c2_W2, c2_b2, nullptr, batch, pooled, 128, n);

  // ---------------- readout ----------------
  lin1_kernel<<<GNUM / 8, 512, 0, stream>>>(pooled, lin1_W, lin1_b, out1b);
  lin2_kernel<<<GNUM, 64, 0, stream>>>(out1b, lin2_W, lin2_b, (float*)d_out);
}

// Round 3
// 727.952 us; speedup vs baseline: 1.3003x; 1.3003x over previous
//
#include <hip/hip_runtime.h>

#define D 128
#define GNUM 512

// ---------------- CSR build: degree histogram ----------------
__global__ void deg_kernel(const int* __restrict__ ei, int* __restrict__ deg,
                           int nE) {
  int e = blockIdx.x * blockDim.x + threadIdx.x;
  if (e < nE) atomicAdd(&deg[ei[nE + e]], 1);
}

// ---------------- CSR build: exclusive scan (single block) ----------------
__global__ __launch_bounds__(1024) void scan_kernel(const int* __restrict__ deg,
                                                    int* __restrict__ rowptr,
                                                    int* __restrict__ cursor,
                                                    int n) {
  __shared__ int sh[1024];
  const int t = threadIdx.x;
  const int c = (n + 1023) >> 10;
  const int i0 = t * c, i1 = min(i0 + c, n);
  int s = 0;
  for (int i = i0; i < i1; i++) s += deg[i];
  sh[t] = s;
  __syncthreads();
  for (int off = 1; off < 1024; off <<= 1) {  // Kogge-Stone inclusive
    int v = (t >= off) ? sh[t - off] : 0;
    __syncthreads();
    sh[t] += v;
    __syncthreads();
  }
  int base = (t == 0) ? 0 : sh[t - 1];
  for (int i = i0; i < i1; i++) {
    int d = deg[i];
    rowptr[i] = base;
    cursor[i] = base;
    base += d;
  }
  if (t == 1023) rowptr[n] = sh[1023];
}

// ---------------- CSR build: fill src lists ----------------
__global__ void fill_kernel(const int* __restrict__ ei, int* __restrict__ cursor,
                            int* __restrict__ csr, int nE) {
  int e = blockIdx.x * blockDim.x + threadIdx.x;
  if (e < nE) {
    int d = ei[nE + e];
    int pos = atomicAdd(&cursor[d], 1);
    csr[pos] = ei[e];
  }
}

// ------- pull aggregation: out[r] = feat[r] + sum_{s in N(r)} feat[s] -----
__global__ __launch_bounds__(256) void agg_kernel(
    const float* __restrict__ feat, const int* __restrict__ rowptr,
    const int* __restrict__ csr, float* __restrict__ out, int n) {
  int row = blockIdx.x * 2 + (threadIdx.x >> 7);
  int c = threadIdx.x & 127;
  if (row >= n) return;
  int beg = rowptr[row], end = rowptr[row + 1];
  float s = feat[(size_t)row * D + c];  // self term (x[dst])
  int j = beg;
  for (; j + 1 < end; j += 2) {  // unroll-2 for load ILP
    int s0 = csr[j], s1 = csr[j + 1];
    s += feat[(size_t)s0 * D + c] + feat[(size_t)s1 * D + c];
  }
  if (j < end) s += feat[(size_t)csr[j] * D + c];
  out[(size_t)row * D + c] = s;
}

// ---------------- GEMM: C[n,128] = f(A)[n,128] @ W[128,128] + b ----------
// MODE 0: f(A) = A; no output activation            (GIN linear1)
// MODE 1: f(A) = relu(A*scale[k] + shift[k]); relu output
// WRITEC: write C rows. POOL: atomically pool relu output into pooled[g][..]
template <int MODE, int WRITEC, int POOL>
__global__ __launch_bounds__(256) void gemm_kernel(
    const float* __restrict__ A,
    const float* __restrict__ X,   // MODE1: scaleshift[256]
    const float* __restrict__ W,
    const float* __restrict__ bias,
    float* __restrict__ C,
    const int* __restrict__ batch,
    float* __restrict__ pooled, int poolbase, int n) {
  __shared__ float Alds[16][132];  // [k][r], padded stride
  __shared__ float Wlds[16][128];  // [k][j]
  const int t = threadIdx.x;
  const int row0 = blockIdx.x * 128;
  const int tr = t >> 4, tc = t & 15;

  float acc[8][8];
#pragma unroll
  for (int i = 0; i < 8; i++)
#pragma unroll
    for (int j = 0; j < 8; j++) acc[i][j] = 0.f;

  for (int k0 = 0; k0 < D; k0 += 16) {
#pragma unroll
    for (int rep = 0; rep < 2; rep++) {
      int idx = t + rep * 256;       // 0..511
      int r = idx >> 2, kq = idx & 3;
      int gr = row0 + r;
      float4 v = make_float4(0.f, 0.f, 0.f, 0.f);
      if (gr < n) {
        v = *(const float4*)(A + (size_t)gr * D + k0 + kq * 4);
        if (MODE == 1) {
          int kk = k0 + kq * 4;
          v.x = fmaxf(0.f, fmaf(v.x, X[kk + 0], X[128 + kk + 0]));
          v.y = fmaxf(0.f, fmaf(v.y, X[kk + 1], X[128 + kk + 1]));
          v.z = fmaxf(0.f, fmaf(v.z, X[kk + 2], X[128 + kk + 2]));
          v.w = fmaxf(0.f, fmaf(v.w, X[kk + 3], X[128 + kk + 3]));
        }
      }
      Alds[kq * 4 + 0][r] = v.x;
      Alds[kq * 4 + 1][r] = v.y;
      Alds[kq * 4 + 2][r] = v.z;
      Alds[kq * 4 + 3][r] = v.w;
    }
#pragma unroll
    for (int rep = 0; rep < 2; rep++) {
      int idx = t + rep * 256;
      int kr = idx >> 5, jq = idx & 31;
      *(float4*)(&Wlds[kr][jq * 4]) =
          *(const float4*)(W + (size_t)(k0 + kr) * D + jq * 4);
    }
    __syncthreads();
#pragma unroll
    for (int k = 0; k < 16; k++) {
      float a[8], w[8];
      *(float4*)(a)     = *(const float4*)(&Alds[k][tr * 8]);
      *(float4*)(a + 4) = *(const float4*)(&Alds[k][tr * 8 + 4]);
      *(float4*)(w)     = *(const float4*)(&Wlds[k][tc * 8]);
      *(float4*)(w + 4) = *(const float4*)(&Wlds[k][tc * 8 + 4]);
#pragma unroll
      for (int i = 0; i < 8; i++)
#pragma unroll
        for (int j = 0; j < 8; j++) acc[i][j] = fmaf(a[i], w[j], acc[i][j]);
    }
    __syncthreads();
  }

  // ---------------- epilogue ----------------
  if constexpr (POOL == 0) {
#pragma unroll
    for (int i = 0; i < 8; i++) {
      int gr = row0 + tr * 8 + i;
      if (gr < n) {
#pragma unroll
        for (int jq = 0; jq < 2; jq++) {
          int col = tc * 8 + jq * 4;
          float4 o;
          o.x = acc[i][jq * 4 + 0] + bias[col + 0];
          o.y = acc[i][jq * 4 + 1] + bias[col + 1];
          o.z = acc[i][jq * 4 + 2] + bias[col + 2];
          o.w = acc[i][jq * 4 + 3] + bias[col + 3];
          if (MODE == 1) {
            o.x = fmaxf(0.f, o.x); o.y = fmaxf(0.f, o.y);
            o.z = fmaxf(0.f, o.z); o.w = fmaxf(0.f, o.w);
          }
          *(float4*)(C + (size_t)gr * D + col) = o;
        }
      }
    }
  } else {
    // MODE==1 here: relu output, pool sum+max per graph.
    const int r0g = row0 + tr * 8;
    int uniform = 0, gu = 0;
    if (r0g + 7 < n) {
      int b0 = batch[r0g], b7 = batch[r0g + 7];
      if (b0 == b7) { uniform = 1; gu = b0; }
    }
#pragma unroll
    for (int jq = 0; jq < 2; jq++) {
      const int col = tc * 8 + jq * 4;
      const float b0 = bias[col], b1 = bias[col + 1];
      const float b2 = bias[col + 2], b3 = bias[col + 3];
      float s0 = 0.f, s1 = 0.f, s2 = 0.f, s3 = 0.f;
      float m0 = 0.f, m1 = 0.f, m2 = 0.f, m3 = 0.f;
#pragma unroll
      for (int i = 0; i < 8; i++) {
        int gr = r0g + i;
        if (gr < n) {
          float o0 = fmaxf(0.f, acc[i][jq * 4 + 0] + b0);
          float o1 = fmaxf(0.f, acc[i][jq * 4 + 1] + b1);
          float o2 = fmaxf(0.f, acc[i][jq * 4 + 2] + b2);
          float o3 = fmaxf(0.f, acc[i][jq * 4 + 3] + b3);
          if constexpr (WRITEC) {
            *(float4*)(C + (size_t)gr * D + col) = make_float4(o0, o1, o2, o3);
          }
          if (uniform) {
            s0 += o0; s1 += o1; s2 += o2; s3 += o3;
            m0 = fmaxf(m0, o0); m1 = fmaxf(m1, o1);
            m2 = fmaxf(m2, o2); m3 = fmaxf(m3, o3);
          } else {
            int g = batch[gr];
            float* ps = pooled + (size_t)g * 512 + poolbase + col;
            atomicAdd(ps + 0, o0); atomicAdd(ps + 1, o1);
            atomicAdd(ps + 2, o2); atomicAdd(ps + 3, o3);
            int* pm = (int*)(pooled + (size_t)g * 512 + poolbase + 256 + col);
            atomicMax(pm + 0, __float_as_int(o0));
            atomicMax(pm + 1, __float_as_int(o1));
            atomicMax(pm + 2, __float_as_int(o2));
            atomicMax(pm + 3, __float_as_int(o3));
          }
        }
      }
      if (uniform) {
        float* ps = pooled + (size_t)gu * 512 + poolbase + col;
        atomicAdd(ps + 0, s0); atomicAdd(ps + 1, s1);
        atomicAdd(ps + 2, s2); atomicAdd(ps + 3, s3);
        int* pm = (int*)(pooled + (size_t)gu * 512 + poolbase + 256 + col);
        atomicMax(pm + 0, __float_as_int(m0));
        atomicMax(pm + 1, __float_as_int(m1));
        atomicMax(pm + 2, __float_as_int(m2));
        atomicMax(pm + 3, __float_as_int(m3));
      }
    }
  }
}

// ------------- per-column sum / sumsq over tmp[n,128] --------------------
__global__ void colreduce_kernel(const float* __restrict__ tmp,
                                 float* __restrict__ colsum, int n) {
  int c = threadIdx.x;  // 128 threads
  int rows_per_block = (n + gridDim.x - 1) / gridDim.x;
  int r0 = blockIdx.x * rows_per_block;
  int r1 = min(r0 + rows_per_block, n);
  float s = 0.f, sq = 0.f;
  for (int r = r0; r < r1; r++) {
    float v = tmp[(size_t)r * D + c];
    s += v;
    sq = fmaf(v, v, sq);
  }
  atomicAdd(colsum + c, s);
  atomicAdd(colsum + 128 + c, sq);
}

// ------------- BN stats -> scale/shift -----------------------------------
__global__ void bnstats_kernel(const float* __restrict__ colsum,
                               const float* __restrict__ g,
                               const float* __restrict__ be,
                               float* __restrict__ ss, int n) {
  int c = threadIdx.x;  // 128
  float inv_n = 1.0f / (float)n;
  float mean = colsum[c] * inv_n;
  float var = colsum[128 + c] * inv_n - mean * mean;
  float scale = g[c] * rsqrtf(var + 1e-5f);
  ss[c] = scale;
  ss[128 + c] = be[c] - mean * scale;
}

// ------------- readout lin1: out1[G,512] = relu(pooled @ W + b) ----------
__global__ __launch_bounds__(512) void lin1_kernel(
    const float* __restrict__ pooled, const float* __restrict__ W,
    const float* __restrict__ b, float* __restrict__ out1) {
  __shared__ float prow[8][512];
  int j = threadIdx.x;
  int g0 = blockIdx.x * 8;
#pragma unroll
  for (int rep = 0; rep < 2; rep++) {
    int idx = threadIdx.x + rep * 512;  // 0..1023 float4 chunks
    int r = idx >> 7;
    int q = idx & 127;
    *(float4*)(&prow[r][q * 4]) =
        *(const float4*)(pooled + (size_t)(g0 + r) * 512 + q * 4);
  }
  __syncthreads();
  float acc[8];
#pragma unroll
  for (int r = 0; r < 8; r++) acc[r] = 0.f;
  for (int k = 0; k < 512; k++) {
    float w = W[(size_t)k * 512 + j];
#pragma unroll
    for (int r = 0; r < 8; r++) acc[r] = fmaf(prow[r][k], w, acc[r]);
  }
  float bj = b[j];
#pragma unroll
  for (int r = 0; r < 8; r++)
    out1[(size_t)(g0 + r) * 512 + j] = fmaxf(0.f, acc[r] + bj);
}

// ------------- readout lin2 + sigmoid ------------------------------------
__global__ void lin2_kernel(const float* __restrict__ out1,
                            const float* __restrict__ W,
                            const float* __restrict__ b,
                            float* __restrict__ out) {
  int g = blockIdx.x;
  int lane = threadIdx.x;  // 64
  float s = 0.f;
  for (int k = lane; k < 512; k += 64)
    s = fmaf(out1[(size_t)g * 512 + k], W[k], s);
#pragma unroll
  for (int off = 32; off > 0; off >>= 1) s += __shfl_down(s, off);
  if (lane == 0) {
    float h = s + b[0];
    out[g] = 1.0f / (1.0f + expf(-h));
    out[GNUM + g] = h;
  }
}

extern "C" void kernel_launch(void* const* d_in, const int* in_sizes, int n_in,
                              void* d_out, int out_size, void* d_ws,
                              size_t ws_size, hipStream_t stream) {
  const float* x = (const float*)d_in[0];
  const int* ei = (const int*)d_in[1];
  const int* batch = (const int*)d_in[2];
  const float* c1_W1 = (const float*)d_in[3];
  const float* c1_b1 = (const float*)d_in[4];
  const float* c1_g  = (const float*)d_in[5];
  const float* c1_be = (const float*)d_in[6];
  const float* c1_W2 = (const float*)d_in[7];
  const float* c1_b2 = (const float*)d_in[8];
  const float* c2_W1 = (const float*)d_in[9];
  const float* c2_b1 = (const float*)d_in[10];
  const float* c2_g  = (const float*)d_in[11];
  const float* c2_be = (const float*)d_in[12];
  const float* c2_W2 = (const float*)d_in[13];
  const float* c2_b2 = (const float*)d_in[14];
  const float* lin1_W = (const float*)d_in[15];
  const float* lin1_b = (const float*)d_in[16];
  const float* lin2_W = (const float*)d_in[17];
  const float* lin2_b = (const float*)d_in[18];

  const int n = in_sizes[0] / D;        // 50000
  const int nE = in_sizes[1] / 2;       // 600000

  float* ws = (float*)d_ws;
  float* aggtmp = ws;                       // n*D
  float* h1 = aggtmp + (size_t)n * D;       // n*D
  float* pooled = h1 + (size_t)n * D;       // GNUM*512
  float* out1b  = pooled + (size_t)GNUM * 512;  // GNUM*512
  float* colsum = out1b + (size_t)GNUM * 512;   // 256
  int* deg    = (int*)(colsum + 256);       // n
  int* rowptr = deg + n;                    // n+1
  int* cursor = rowptr + (n + 1);           // n+1
  int* csr    = cursor + (n + 1);           // nE
  // total ~56 MB

  const int gemm_grid = (n + 127) / 128;
  const int edge_grid = (nE + 255) / 256;
  const int agg_grid = (n + 1) / 2;

  // ---------------- CSR build (shared by both layers) ----------------
  hipMemsetAsync(deg, 0, (size_t)n * sizeof(int), stream);
  hipMemsetAsync(pooled, 0, (size_t)GNUM * 512 * sizeof(float), stream);
  deg_kernel<<<edge_grid, 256, 0, stream>>>(ei, deg, nE);
  scan_kernel<<<1, 1024, 0, stream>>>(deg, rowptr, cursor, n);
  fill_kernel<<<edge_grid, 256, 0, stream>>>(ei, cursor, csr, nE);

  // ---------------- layer 1 ----------------
  agg_kernel<<<agg_grid, 256, 0, stream>>>(x, rowptr, csr, aggtmp, n);
  gemm_kernel<0, 1, 0><<<gemm_grid, 256, 0, stream>>>(
      aggtmp, nullptr, c1_W1, c1_b1, aggtmp, nullptr, nullptr, 0, n);
  hipMemsetAsync(colsum, 0, 256 * sizeof(float), stream);
  colreduce_kernel<<<256, 128, 0, stream>>>(aggtmp, colsum, n);
  bnstats_kernel<<<1, 128, 0, stream>>>(colsum, c1_g, c1_be, colsum, n);
  gemm_kernel<1, 1, 1><<<gemm_grid, 256, 0, stream>>>(
      aggtmp, colsum, c1_W2, c1_b2, h1, batch, pooled, 0, n);

  // ---------------- layer 2 ----------------
  agg_kernel<<<agg_grid, 256, 0, stream>>>(h1, rowptr, csr, aggtmp, n);
  gemm_kernel<0, 1, 0><<<gemm_grid, 256, 0, stream>>>(
      aggtmp, nullptr, c2_W1, c2_b1, aggtmp, nullptr, nullptr, 0, n);
  hipMemsetAsync(colsum, 0, 256 * sizeof(float), stream);
  colreduce_kernel<<<256, 128, 0, stream>>>(aggtmp, colsum, n);
  bnstats_kernel<<<1, 128, 0, stream>>>(colsum, c2_g, c2_be, colsum, n);
  gemm_kernel<1, 0, 1><<<gemm_grid, 256, 0, stream>>>(
      aggtmp, colsum, c2_W2, c2_b2, nullptr, batch, pooled, 128, n);

  // ---------------- readout ----------------
  lin1_kernel<<<GNUM / 8, 512, 0, stream>>>(pooled, lin1_W, lin1_b, out1b);
  lin2_kernel<<<GNUM, 64, 0, stream>>>(out1b, lin2_W, lin2_b, (float*)d_out);
}

// Round 4
// 623.807 us; speedup vs baseline: 1.5173x; 1.1670x over previous
//
#include <hip/hip_runtime.h>

#define D 128
#define GNUM 512

// ---------------- CSR build: degree histogram ----------------
__global__ void deg_kernel(const int* __restrict__ ei, int* __restrict__ deg,
                           int nE) {
  int e = blockIdx.x * blockDim.x + threadIdx.x;
  if (e < nE) atomicAdd(&deg[ei[nE + e]], 1);
}

// ------------- hierarchical scan: per-block partial sums ------------------
// block b sums deg[b*512 .. b*512+511]
__global__ __launch_bounds__(256) void partial_kernel(
    const int* __restrict__ deg, int* __restrict__ partials, int n) {
  __shared__ int sh[256];
  const int t = threadIdx.x;
  const int i = blockIdx.x * 512 + t * 2;
  int s = 0;
  if (i < n) s += deg[i];
  if (i + 1 < n) s += deg[i + 1];
  sh[t] = s;
  __syncthreads();
#pragma unroll
  for (int off = 128; off > 0; off >>= 1) {
    if (t < off) sh[t] += sh[t + off];
    __syncthreads();
  }
  if (t == 0) partials[blockIdx.x] = sh[0];
}

// ------------- hierarchical scan: scan the partials (1 block) -------------
__global__ __launch_bounds__(128) void scanp_kernel(
    int* __restrict__ partials, int nP, int* __restrict__ rowptr, int n,
    int nE) {
  __shared__ int sh[128];
  const int t = threadIdx.x;
  const int v = (t < nP) ? partials[t] : 0;
  sh[t] = v;
  __syncthreads();
#pragma unroll
  for (int off = 1; off < 128; off <<= 1) {  // Kogge-Stone inclusive
    int u = (t >= off) ? sh[t - off] : 0;
    __syncthreads();
    sh[t] += u;
    __syncthreads();
  }
  if (t < nP) partials[t] = sh[t] - v;  // exclusive block offset
  if (t == 0) rowptr[n] = nE;           // every edge has dst in [0,n)
}

// ------------- hierarchical scan: emit rowptr/cursor ----------------------
__global__ __launch_bounds__(256) void emit_kernel(
    const int* __restrict__ deg, const int* __restrict__ partials,
    int* __restrict__ rowptr, int* __restrict__ cursor, int n) {
  __shared__ int sh[256];
  const int t = threadIdx.x;
  const int i = blockIdx.x * 512 + t * 2;
  const int d0 = (i < n) ? deg[i] : 0;
  const int d1 = (i + 1 < n) ? deg[i + 1] : 0;
  const int s = d0 + d1;
  sh[t] = s;
  __syncthreads();
#pragma unroll
  for (int off = 1; off < 256; off <<= 1) {  // Kogge-Stone inclusive
    int u = (t >= off) ? sh[t - off] : 0;
    __syncthreads();
    sh[t] += u;
    __syncthreads();
  }
  int base = partials[blockIdx.x] + sh[t] - s;  // exclusive within block
  if (i < n) {
    rowptr[i] = base;
    cursor[i] = base;
    base += d0;
  }
  if (i + 1 < n) {
    rowptr[i + 1] = base;
    cursor[i + 1] = base;
  }
}

// ---------------- CSR build: fill src lists ----------------
__global__ void fill_kernel(const int* __restrict__ ei, int* __restrict__ cursor,
                            int* __restrict__ csr, int nE) {
  int e = blockIdx.x * blockDim.x + threadIdx.x;
  if (e < nE) {
    int d = ei[nE + e];
    int pos = atomicAdd(&cursor[d], 1);
    csr[pos] = ei[e];
  }
}

// ------- pull aggregation: out[r] = feat[r] + sum_{s in N(r)} feat[s] -----
__global__ __launch_bounds__(256) void agg_kernel(
    const float* __restrict__ feat, const int* __restrict__ rowptr,
    const int* __restrict__ csr, float* __restrict__ out, int n) {
  int row = blockIdx.x * 2 + (threadIdx.x >> 7);
  int c = threadIdx.x & 127;
  if (row >= n) return;
  int beg = rowptr[row], end = rowptr[row + 1];
  float s = feat[(size_t)row * D + c];  // self term (x[dst])
  int j = beg;
  for (; j + 1 < end; j += 2) {  // unroll-2 for load ILP
    int s0 = csr[j], s1 = csr[j + 1];
    s += feat[(size_t)s0 * D + c] + feat[(size_t)s1 * D + c];
  }
  if (j < end) s += feat[(size_t)csr[j] * D + c];
  out[(size_t)row * D + c] = s;
}

// ---------------- GEMM: C[n,128] = f(A)[n,128] @ W[128,128] + b ----------
// MODE 0: f(A) = A; no output activation            (GIN linear1)
// MODE 1: f(A) = relu(A*scale[k] + shift[k]); relu output
// WRITEC: write C rows. POOL: atomically pool relu output into pooled[g][..]
template <int MODE, int WRITEC, int POOL>
__global__ __launch_bounds__(256) void gemm_kernel(
    const float* __restrict__ A,
    const float* __restrict__ X,   // MODE1: scaleshift[256]
    const float* __restrict__ W,
    const float* __restrict__ bias,
    float* __restrict__ C,
    const int* __restrict__ batch,
    float* __restrict__ pooled, int poolbase, int n) {
  __shared__ float Alds[16][132];  // [k][r], padded stride
  __shared__ float Wlds[16][128];  // [k][j]
  const int t = threadIdx.x;
  const int row0 = blockIdx.x * 128;
  const int tr = t >> 4, tc = t & 15;

  float acc[8][8];
#pragma unroll
  for (int i = 0; i < 8; i++)
#pragma unroll
    for (int j = 0; j < 8; j++) acc[i][j] = 0.f;

  for (int k0 = 0; k0 < D; k0 += 16) {
#pragma unroll
    for (int rep = 0; rep < 2; rep++) {
      int idx = t + rep * 256;       // 0..511
      int r = idx >> 2, kq = idx & 3;
      int gr = row0 + r;
      float4 v = make_float4(0.f, 0.f, 0.f, 0.f);
      if (gr < n) {
        v = *(const float4*)(A + (size_t)gr * D + k0 + kq * 4);
        if (MODE == 1) {
          int kk = k0 + kq * 4;
          v.x = fmaxf(0.f, fmaf(v.x, X[kk + 0], X[128 + kk + 0]));
          v.y = fmaxf(0.f, fmaf(v.y, X[kk + 1], X[128 + kk + 1]));
          v.z = fmaxf(0.f, fmaf(v.z, X[kk + 2], X[128 + kk + 2]));
          v.w = fmaxf(0.f, fmaf(v.w, X[kk + 3], X[128 + kk + 3]));
        }
      }
      Alds[kq * 4 + 0][r] = v.x;
      Alds[kq * 4 + 1][r] = v.y;
      Alds[kq * 4 + 2][r] = v.z;
      Alds[kq * 4 + 3][r] = v.w;
    }
#pragma unroll
    for (int rep = 0; rep < 2; rep++) {
      int idx = t + rep * 256;
      int kr = idx >> 5, jq = idx & 31;
      *(float4*)(&Wlds[kr][jq * 4]) =
          *(const float4*)(W + (size_t)(k0 + kr) * D + jq * 4);
    }
    __syncthreads();
#pragma unroll
    for (int k = 0; k < 16; k++) {
      float a[8], w[8];
      *(float4*)(a)     = *(const float4*)(&Alds[k][tr * 8]);
      *(float4*)(a + 4) = *(const float4*)(&Alds[k][tr * 8 + 4]);
      *(float4*)(w)     = *(const float4*)(&Wlds[k][tc * 8]);
      *(float4*)(w + 4) = *(const float4*)(&Wlds[k][tc * 8 + 4]);
#pragma unroll
      for (int i = 0; i < 8; i++)
#pragma unroll
        for (int j = 0; j < 8; j++) acc[i][j] = fmaf(a[i], w[j], acc[i][j]);
    }
    __syncthreads();
  }

  // ---------------- epilogue ----------------
  if constexpr (POOL == 0) {
#pragma unroll
    for (int i = 0; i < 8; i++) {
      int gr = row0 + tr * 8 + i;
      if (gr < n) {
#pragma unroll
        for (int jq = 0; jq < 2; jq++) {
          int col = tc * 8 + jq * 4;
          float4 o;
          o.x = acc[i][jq * 4 + 0] + bias[col + 0];
          o.y = acc[i][jq * 4 + 1] + bias[col + 1];
          o.z = acc[i][jq * 4 + 2] + bias[col + 2];
          o.w = acc[i][jq * 4 + 3] + bias[col + 3];
          if (MODE == 1) {
            o.x = fmaxf(0.f, o.x); o.y = fmaxf(0.f, o.y);
            o.z = fmaxf(0.f, o.z); o.w = fmaxf(0.f, o.w);
          }
          *(float4*)(C + (size_t)gr * D + col) = o;
        }
      }
    }
  } else {
    // MODE==1 here: relu output, pool sum+max per graph.
    const int r0g = row0 + tr * 8;
    int uniform = 0, gu = 0;
    if (r0g + 7 < n) {
      int b0 = batch[r0g], b7 = batch[r0g + 7];
      if (b0 == b7) { uniform = 1; gu = b0; }
    }
#pragma unroll
    for (int jq = 0; jq < 2; jq++) {
      const int col = tc * 8 + jq * 4;
      const float b0 = bias[col], b1 = bias[col + 1];
      const float b2 = bias[col + 2], b3 = bias[col + 3];
      float s0 = 0.f, s1 = 0.f, s2 = 0.f, s3 = 0.f;
      float m0 = 0.f, m1 = 0.f, m2 = 0.f, m3 = 0.f;
#pragma unroll
      for (int i = 0; i < 8; i++) {
        int gr = r0g + i;
        if (gr < n) {
          float o0 = fmaxf(0.f, acc[i][jq * 4 + 0] + b0);
          float o1 = fmaxf(0.f, acc[i][jq * 4 + 1] + b1);
          float o2 = fmaxf(0.f, acc[i][jq * 4 + 2] + b2);
          float o3 = fmaxf(0.f, acc[i][jq * 4 + 3] + b3);
          if constexpr (WRITEC) {
            *(float4*)(C + (size_t)gr * D + col) = make_float4(o0, o1, o2, o3);
          }
          if (uniform) {
            s0 += o0; s1 += o1; s2 += o2; s3 += o3;
            m0 = fmaxf(m0, o0); m1 = fmaxf(m1, o1);
            m2 = fmaxf(m2, o2); m3 = fmaxf(m3, o3);
          } else {
            int g = batch[gr];
            float* ps = pooled + (size_t)g * 512 + poolbase + col;
            atomicAdd(ps + 0, o0); atomicAdd(ps + 1, o1);
            atomicAdd(ps + 2, o2); atomicAdd(ps + 3, o3);
            int* pm = (int*)(pooled + (size_t)g * 512 + poolbase + 256 + col);
            atomicMax(pm + 0, __float_as_int(o0));
            atomicMax(pm + 1, __float_as_int(o1));
            atomicMax(pm + 2, __float_as_int(o2));
            atomicMax(pm + 3, __float_as_int(o3));
          }
        }
      }
      if (uniform) {
        float* ps = pooled + (size_t)gu * 512 + poolbase + col;
        atomicAdd(ps + 0, s0); atomicAdd(ps + 1, s1);
        atomicAdd(ps + 2, s2); atomicAdd(ps + 3, s3);
        int* pm = (int*)(pooled + (size_t)gu * 512 + poolbase + 256 + col);
        atomicMax(pm + 0, __float_as_int(m0));
        atomicMax(pm + 1, __float_as_int(m1));
        atomicMax(pm + 2, __float_as_int(m2));
        atomicMax(pm + 3, __float_as_int(m3));
      }
    }
  }
}

// ------------- per-column sum / sumsq over tmp[n,128] --------------------
__global__ void colreduce_kernel(const float* __restrict__ tmp,
                                 float* __restrict__ colsum, int n) {
  int c = threadIdx.x;  // 128 threads
  int rows_per_block = (n + gridDim.x - 1) / gridDim.x;
  int r0 = blockIdx.x * rows_per_block;
  int r1 = min(r0 + rows_per_block, n);
  float s = 0.f, sq = 0.f;
  for (int r = r0; r < r1; r++) {
    float v = tmp[(size_t)r * D + c];
    s += v;
    sq = fmaf(v, v, sq);
  }
  atomicAdd(colsum + c, s);
  atomicAdd(colsum + 128 + c, sq);
}

// ------------- BN stats -> scale/shift (in place on colsum) ---------------
__global__ void bnstats_kernel(const float* __restrict__ colsum,
                               const float* __restrict__ g,
                               const float* __restrict__ be,
                               float* __restrict__ ss, int n) {
  int c = threadIdx.x;  // 128
  float inv_n = 1.0f / (float)n;
  float mean = colsum[c] * inv_n;
  float var = colsum[128 + c] * inv_n - mean * mean;
  float scale = g[c] * rsqrtf(var + 1e-5f);
  ss[c] = scale;
  ss[128 + c] = be[c] - mean * scale;
}

// ------------- readout lin1: out1[G,512] = relu(pooled @ W + b) ----------
__global__ __launch_bounds__(512) void lin1_kernel(
    const float* __restrict__ pooled, const float* __restrict__ W,
    const float* __restrict__ b, float* __restrict__ out1) {
  __shared__ float prow[8][512];
  int j = threadIdx.x;
  int g0 = blockIdx.x * 8;
#pragma unroll
  for (int rep = 0; rep < 2; rep++) {
    int idx = threadIdx.x + rep * 512;  // 0..1023 float4 chunks
    int r = idx >> 7;
    int q = idx & 127;
    *(float4*)(&prow[r][q * 4]) =
        *(const float4*)(pooled + (size_t)(g0 + r) * 512 + q * 4);
  }
  __syncthreads();
  float acc[8];
#pragma unroll
  for (int r = 0; r < 8; r++) acc[r] = 0.f;
  for (int k = 0; k < 512; k++) {
    float w = W[(size_t)k * 512 + j];
#pragma unroll
    for (int r = 0; r < 8; r++) acc[r] = fmaf(prow[r][k], w, acc[r]);
  }
  float bj = b[j];
#pragma unroll
  for (int r = 0; r < 8; r++)
    out1[(size_t)(g0 + r) * 512 + j] = fmaxf(0.f, acc[r] + bj);
}

// ------------- readout lin2 + sigmoid ------------------------------------
__global__ void lin2_kernel(const float* __restrict__ out1,
                            const float* __restrict__ W,
                            const float* __restrict__ b,
                            float* __restrict__ out) {
  int g = blockIdx.x;
  int lane = threadIdx.x;  // 64
  float s = 0.f;
  for (int k = lane; k < 512; k += 64)
    s = fmaf(out1[(size_t)g * 512 + k], W[k], s);
#pragma unroll
  for (int off = 32; off > 0; off >>= 1) s += __shfl_down(s, off);
  if (lane == 0) {
    float h = s + b[0];
    out[g] = 1.0f / (1.0f + expf(-h));
    out[GNUM + g] = h;
  }
}

extern "C" void kernel_launch(void* const* d_in, const int* in_sizes, int n_in,
                              void* d_out, int out_size, void* d_ws,
                              size_t ws_size, hipStream_t stream) {
  const float* x = (const float*)d_in[0];
  const int* ei = (const int*)d_in[1];
  const int* batch = (const int*)d_in[2];
  const float* c1_W1 = (const float*)d_in[3];
  const float* c1_b1 = (const float*)d_in[4];
  const float* c1_g  = (const float*)d_in[5];
  const float* c1_be = (const float*)d_in[6];
  const float* c1_W2 = (const float*)d_in[7];
  const float* c1_b2 = (const float*)d_in[8];
  const float* c2_W1 = (const float*)d_in[9];
  const float* c2_b1 = (const float*)d_in[10];
  const float* c2_g  = (const float*)d_in[11];
  const float* c2_be = (const float*)d_in[12];
  const float* c2_W2 = (const float*)d_in[13];
  const float* c2_b2 = (const float*)d_in[14];
  const float* lin1_W = (const float*)d_in[15];
  const float* lin1_b = (const float*)d_in[16];
  const float* lin2_W = (const float*)d_in[17];
  const float* lin2_b = (const float*)d_in[18];

  const int n = in_sizes[0] / D;        // 50000
  const int nE = in_sizes[1] / 2;       // 600000

  float* ws = (float*)d_ws;
  float* aggtmp = ws;                       // n*D
  float* h1 = aggtmp + (size_t)n * D;       // n*D
  float* pooled = h1 + (size_t)n * D;       // GNUM*512
  float* out1b  = pooled + (size_t)GNUM * 512;  // GNUM*512
  float* colsum = out1b + (size_t)GNUM * 512;   // 256
  int* deg      = (int*)(colsum + 256);     // n
  int* rowptr   = deg + n;                  // n+1
  int* cursor   = rowptr + (n + 1);         // n+1
  int* partials = cursor + (n + 1);         // <=128
  int* csr      = partials + 128;           // nE
  // total ~56 MB

  const int gemm_grid = (n + 127) / 128;
  const int edge_grid = (nE + 255) / 256;
  const int agg_grid = (n + 1) / 2;
  const int nP = (n + 511) / 512;           // 98 (must be <=128)

  // ---------------- CSR build (shared by both layers) ----------------
  hipMemsetAsync(deg, 0, (size_t)n * sizeof(int), stream);
  hipMemsetAsync(pooled, 0, (size_t)GNUM * 512 * sizeof(float), stream);
  deg_kernel<<<edge_grid, 256, 0, stream>>>(ei, deg, nE);
  partial_kernel<<<nP, 256, 0, stream>>>(deg, partials, n);
  scanp_kernel<<<1, 128, 0, stream>>>(partials, nP, rowptr, n, nE);
  emit_kernel<<<nP, 256, 0, stream>>>(deg, partials, rowptr, cursor, n);
  fill_kernel<<<edge_grid, 256, 0, stream>>>(ei, cursor, csr, nE);

  // ---------------- layer 1 ----------------
  agg_kernel<<<agg_grid, 256, 0, stream>>>(x, rowptr, csr, aggtmp, n);
  gemm_kernel<0, 1, 0><<<gemm_grid, 256, 0, stream>>>(
      aggtmp, nullptr, c1_W1, c1_b1, aggtmp, nullptr, nullptr, 0, n);
  hipMemsetAsync(colsum, 0, 256 * sizeof(float), stream);
  colreduce_kernel<<<256, 128, 0, stream>>>(aggtmp, colsum, n);
  bnstats_kernel<<<1, 128, 0, stream>>>(colsum, c1_g, c1_be, colsum, n);
  gemm_kernel<1, 1, 1><<<gemm_grid, 256, 0, stream>>>(
      aggtmp, colsum, c1_W2, c1_b2, h1, batch, pooled, 0, n);

  // ---------------- layer 2 ----------------
  agg_kernel<<<agg_grid, 256, 0, stream>>>(h1, rowptr, csr, aggtmp, n);
  gemm_kernel<0, 1, 0><<<gemm_grid, 256, 0, stream>>>(
      aggtmp, nullptr, c2_W1, c2_b1, aggtmp, nullptr, nullptr, 0, n);
  hipMemsetAsync(colsum, 0, 256 * sizeof(float), stream);
  colreduce_kernel<<<256, 128, 0, stream>>>(aggtmp, colsum, n);
  bnstats_kernel<<<1, 128, 0, stream>>>(colsum, c2_g, c2_be, colsum, n);
  gemm_kernel<1, 0, 1><<<gemm_grid, 256, 0, stream>>>(
      aggtmp, colsum, c2_W2, c2_b2, nullptr, batch, pooled, 128, n);

  // ---------------- readout ----------------
  lin1_kernel<<<GNUM / 8, 512, 0, stream>>>(pooled, lin1_W, lin1_b, out1b);
  lin2_kernel<<<GNUM, 64, 0, stream>>>(out1b, lin2_W, lin2_b, (float*)d_out);
}

// Round 5
// 445.631 us; speedup vs baseline: 2.1240x; 1.3998x over previous
//
#include <hip/hip_runtime.h>

#define D 128
#define GNUM 512

typedef _Float16 f16;
typedef _Float16 f16x8 __attribute__((ext_vector_type(8)));
typedef float f32x4 __attribute__((ext_vector_type(4)));

// ---------------- CSR build: degree histogram ----------------
__global__ void deg_kernel(const int* __restrict__ ei, int* __restrict__ deg,
                           int nE) {
  int e = blockIdx.x * blockDim.x + threadIdx.x;
  if (e < nE) atomicAdd(&deg[ei[nE + e]], 1);
}

// ------------- hierarchical scan: per-block partial sums ------------------
__global__ __launch_bounds__(256) void partial_kernel(
    const int* __restrict__ deg, int* __restrict__ partials, int n) {
  __shared__ int sh[256];
  const int t = threadIdx.x;
  const int i = blockIdx.x * 512 + t * 2;
  int s = 0;
  if (i < n) s += deg[i];
  if (i + 1 < n) s += deg[i + 1];
  sh[t] = s;
  __syncthreads();
#pragma unroll
  for (int off = 128; off > 0; off >>= 1) {
    if (t < off) sh[t] += sh[t + off];
    __syncthreads();
  }
  if (t == 0) partials[blockIdx.x] = sh[0];
}

// ------------- hierarchical scan: scan the partials (1 block) -------------
__global__ __launch_bounds__(128) void scanp_kernel(
    int* __restrict__ partials, int nP, int* __restrict__ rowptr, int n,
    int nE) {
  __shared__ int sh[128];
  const int t = threadIdx.x;
  const int v = (t < nP) ? partials[t] : 0;
  sh[t] = v;
  __syncthreads();
#pragma unroll
  for (int off = 1; off < 128; off <<= 1) {
    int u = (t >= off) ? sh[t - off] : 0;
    __syncthreads();
    sh[t] += u;
    __syncthreads();
  }
  if (t < nP) partials[t] = sh[t] - v;
  if (t == 0) rowptr[n] = nE;
}

// ------------- hierarchical scan: emit rowptr/cursor ----------------------
__global__ __launch_bounds__(256) void emit_kernel(
    const int* __restrict__ deg, const int* __restrict__ partials,
    int* __restrict__ rowptr, int* __restrict__ cursor, int n) {
  __shared__ int sh[256];
  const int t = threadIdx.x;
  const int i = blockIdx.x * 512 + t * 2;
  const int d0 = (i < n) ? deg[i] : 0;
  const int d1 = (i + 1 < n) ? deg[i + 1] : 0;
  const int s = d0 + d1;
  sh[t] = s;
  __syncthreads();
#pragma unroll
  for (int off = 1; off < 256; off <<= 1) {
    int u = (t >= off) ? sh[t - off] : 0;
    __syncthreads();
    sh[t] += u;
    __syncthreads();
  }
  int base = partials[blockIdx.x] + sh[t] - s;
  if (i < n) {
    rowptr[i] = base;
    cursor[i] = base;
    base += d0;
  }
  if (i + 1 < n) {
    rowptr[i + 1] = base;
    cursor[i + 1] = base;
  }
}

// ---------------- CSR build: fill src lists ----------------
__global__ void fill_kernel(const int* __restrict__ ei, int* __restrict__ cursor,
                            int* __restrict__ csr, int nE) {
  int e = blockIdx.x * blockDim.x + threadIdx.x;
  if (e < nE) {
    int d = ei[nE + e];
    int pos = atomicAdd(&cursor[d], 1);
    csr[pos] = ei[e];
  }
}

// ---------------- fp32 -> f16 convert (x once per call) -------------------
__global__ void xcvt_kernel(const float* __restrict__ in, f16* __restrict__ out,
                            int n4) {
  int i = blockIdx.x * 256 + threadIdx.x;
  if (i < n4) {
    float4 v = ((const float4*)in)[i];
    union { f16 h[4]; uint2 u; } p;
    p.h[0] = (f16)v.x; p.h[1] = (f16)v.y; p.h[2] = (f16)v.z; p.h[3] = (f16)v.w;
    ((uint2*)out)[i] = p.u;
  }
}

// ---------------- weight prep: W_T[w][col][k] = (f16)W_w[k][col] ----------
__global__ void wprep_kernel(const float* __restrict__ W0,
                             const float* __restrict__ W1,
                             const float* __restrict__ W2,
                             const float* __restrict__ W3,
                             f16* __restrict__ out) {
  int idx = blockIdx.x * 256 + threadIdx.x;  // 65536 total
  int wsel = idx >> 14;                      // uniform per block (64 blocks each)
  int rem = idx & 16383;
  int col = rem >> 7, k = rem & 127;
  const float* W = (wsel == 0) ? W0 : (wsel == 1) ? W1 : (wsel == 2) ? W2 : W3;
  out[idx] = (f16)W[k * D + col];
}

// ------- pull aggregation (f16 in/out): out[r] = f[r] + sum f[N(r)] -------
__global__ __launch_bounds__(256) void agg16_kernel(
    const f16* __restrict__ feat, const int* __restrict__ rowptr,
    const int* __restrict__ csr, f16* __restrict__ out, int n) {
  int row = blockIdx.x * 16 + (threadIdx.x >> 4);
  int q = threadIdx.x & 15;  // 8-element group
  if (row >= n) return;
  const int co = q * 8;
  float a[8];
  f16x8 v = *(const f16x8*)(feat + (size_t)row * D + co);
#pragma unroll
  for (int j = 0; j < 8; j++) a[j] = (float)v[j];
  int beg = rowptr[row], end = rowptr[row + 1];
  int i = beg;
  for (; i + 1 < end; i += 2) {
    int s0 = csr[i], s1 = csr[i + 1];
    f16x8 v0 = *(const f16x8*)(feat + (size_t)s0 * D + co);
    f16x8 v1 = *(const f16x8*)(feat + (size_t)s1 * D + co);
#pragma unroll
    for (int j = 0; j < 8; j++) a[j] += (float)v0[j] + (float)v1[j];
  }
  if (i < end) {
    f16x8 v0 = *(const f16x8*)(feat + (size_t)csr[i] * D + co);
#pragma unroll
    for (int j = 0; j < 8; j++) a[j] += (float)v0[j];
  }
  f16x8 o;
#pragma unroll
  for (int j = 0; j < 8; j++) o[j] = (f16)a[j];
  *(f16x8*)(out + (size_t)row * D + co) = o;
}

// ---------------- MFMA GEMM: C[n,128] = f(A)[n,128] @ W[128,128] + b ------
// AF16: A is f16 (plain). else A is f32 with BN scale/shift + relu on load.
// OUT 0: C fp32 = A@W + b (no act).  OUT 1: relu, store f16 C, pool@pb.
// OUT 2: relu, pool@pb only.
// Block: 256 thr = 4 waves; wave w owns rows [blk*128 + w*32, +32), all cols.
template <int AF16, int OUT>
__global__ __launch_bounds__(256) void gemm16_kernel(
    const void* __restrict__ Ain, const float* __restrict__ ss,
    const f16* __restrict__ WT, const float* __restrict__ bias,
    void* __restrict__ Cout, const int* __restrict__ batch,
    float* __restrict__ pooled, int pb, int n) {
  const int l = threadIdx.x & 63;
  const int w = threadIdx.x >> 6;
  const int rw0 = blockIdx.x * 128 + w * 32;
  const int lr = l & 15;
  const int lq = l >> 4;
  const int lk = lq * 8;

  f32x4 acc[2][8];
#pragma unroll
  for (int m = 0; m < 2; m++)
#pragma unroll
    for (int nt = 0; nt < 8; nt++) acc[m][nt] = (f32x4)0.f;

#pragma unroll
  for (int s = 0; s < 4; s++) {
    const int k = s * 32 + lk;
    // ---- A fragments (2 m-tiles) ----
    f16x8 af[2];
#pragma unroll
    for (int m = 0; m < 2; m++) {
      int row = rw0 + m * 16 + lr;
      if (AF16) {
        af[m] = (row < n)
                    ? *(const f16x8*)((const f16*)Ain + (size_t)row * D + k)
                    : (f16x8)(f16)0.f;
      } else {
        float4 u0 = make_float4(0.f, 0.f, 0.f, 0.f), u1 = u0;
        if (row < n) {
          const float* ap = (const float*)Ain + (size_t)row * D + k;
          u0 = *(const float4*)ap;
          u1 = *(const float4*)(ap + 4);
        }
        float4 c0 = *(const float4*)(ss + k);
        float4 c1 = *(const float4*)(ss + k + 4);
        float4 h0 = *(const float4*)(ss + 128 + k);
        float4 h1 = *(const float4*)(ss + 128 + k + 4);
        f16x8 r;
        r[0] = (f16)fmaxf(0.f, fmaf(u0.x, c0.x, h0.x));
        r[1] = (f16)fmaxf(0.f, fmaf(u0.y, c0.y, h0.y));
        r[2] = (f16)fmaxf(0.f, fmaf(u0.z, c0.z, h0.z));
        r[3] = (f16)fmaxf(0.f, fmaf(u0.w, c0.w, h0.w));
        r[4] = (f16)fmaxf(0.f, fmaf(u1.x, c1.x, h1.x));
        r[5] = (f16)fmaxf(0.f, fmaf(u1.y, c1.y, h1.y));
        r[6] = (f16)fmaxf(0.f, fmaf(u1.z, c1.z, h1.z));
        r[7] = (f16)fmaxf(0.f, fmaf(u1.w, c1.w, h1.w));
        af[m] = r;
      }
    }
    // ---- B fragments (8 n-tiles) from W_T (L2-resident) ----
    f16x8 bf[8];
#pragma unroll
    for (int nt = 0; nt < 8; nt++) {
      int col = nt * 16 + lr;
      bf[nt] = *(const f16x8*)(WT + (size_t)col * D + k);
    }
#pragma unroll
    for (int m = 0; m < 2; m++)
#pragma unroll
      for (int nt = 0; nt < 8; nt++)
        acc[m][nt] = __builtin_amdgcn_mfma_f32_16x16x32_f16(af[m], bf[nt],
                                                            acc[m][nt], 0, 0, 0);
  }

  // ---------------- epilogue ----------------
  if constexpr (OUT == 0) {
#pragma unroll
    for (int m = 0; m < 2; m++)
#pragma unroll
      for (int r = 0; r < 4; r++) {
        int row = rw0 + m * 16 + lq * 4 + r;
        if (row < n) {
          float* cp = (float*)Cout + (size_t)row * D + lr;
#pragma unroll
          for (int nt = 0; nt < 8; nt++)
            cp[nt * 16] = acc[m][nt][r] + bias[nt * 16 + lr];
        }
      }
  } else {
    float bv[8];
#pragma unroll
    for (int nt = 0; nt < 8; nt++) bv[nt] = bias[nt * 16 + lr];
    bool uni = (rw0 + 31 < n) && (batch[rw0] == batch[rw0 + 31]);
    if (uni) {
      int g = batch[rw0];
#pragma unroll
      for (int nt = 0; nt < 8; nt++) {
        float sum = 0.f, mx = 0.f;
#pragma unroll
        for (int m = 0; m < 2; m++)
#pragma unroll
          for (int r = 0; r < 4; r++) {
            float v = fmaxf(0.f, acc[m][nt][r] + bv[nt]);
            if (OUT == 1) {
              int row = rw0 + m * 16 + lq * 4 + r;
              ((f16*)Cout)[(size_t)row * D + nt * 16 + lr] = (f16)v;
            }
            sum += v;
            mx = fmaxf(mx, v);
          }
        sum += __shfl_xor(sum, 16);
        sum += __shfl_xor(sum, 32);
        mx = fmaxf(mx, __shfl_xor(mx, 16));
        mx = fmaxf(mx, __shfl_xor(mx, 32));
        if (l < 16) {
          float* pg = pooled + (size_t)g * 512 + pb + nt * 16 + l;
          atomicAdd(pg, sum);
          atomicMax((int*)(pg + 256), __float_as_int(mx));
        }
      }
    } else {
#pragma unroll
      for (int m = 0; m < 2; m++)
#pragma unroll
        for (int r = 0; r < 4; r++) {
          int row = rw0 + m * 16 + lq * 4 + r;
          if (row < n) {
            int g = batch[row];
            float* pg = pooled + (size_t)g * 512 + pb;
#pragma unroll
            for (int nt = 0; nt < 8; nt++) {
              float v = fmaxf(0.f, acc[m][nt][r] + bv[nt]);
              if (OUT == 1)
                ((f16*)Cout)[(size_t)row * D + nt * 16 + lr] = (f16)v;
              atomicAdd(pg + nt * 16 + lr, v);
              atomicMax((int*)(pg + 256 + nt * 16 + lr), __float_as_int(v));
            }
          }
        }
    }
  }
}

// ------------- per-column sum / sumsq over tmp[n,128] (fp32) --------------
__global__ void colreduce_kernel(const float* __restrict__ tmp,
                                 float* __restrict__ colsum, int n) {
  int c = threadIdx.x;  // 128
  int rows_per_block = (n + gridDim.x - 1) / gridDim.x;
  int r0 = blockIdx.x * rows_per_block;
  int r1 = min(r0 + rows_per_block, n);
  float s = 0.f, sq = 0.f;
  for (int r = r0; r < r1; r++) {
    float v = tmp[(size_t)r * D + c];
    s += v;
    sq = fmaf(v, v, sq);
  }
  atomicAdd(colsum + c, s);
  atomicAdd(colsum + 128 + c, sq);
}

// ------------- BN stats -> scale/shift (in place on colsum) ---------------
__global__ void bnstats_kernel(const float* __restrict__ colsum,
                               const float* __restrict__ g,
                               const float* __restrict__ be,
                               float* __restrict__ ss, int n) {
  int c = threadIdx.x;  // 128
  float inv_n = 1.0f / (float)n;
  float mean = colsum[c] * inv_n;
  float var = colsum[128 + c] * inv_n - mean * mean;
  float scale = g[c] * rsqrtf(var + 1e-5f);
  ss[c] = scale;
  ss[128 + c] = be[c] - mean * scale;
}

// ------------- readout lin1: out1[G,512] = relu(pooled @ W + b) ----------
__global__ __launch_bounds__(512) void lin1_kernel(
    const float* __restrict__ pooled, const float* __restrict__ W,
    const float* __restrict__ b, float* __restrict__ out1) {
  __shared__ float prow[8][512];
  int j = threadIdx.x;
  int g0 = blockIdx.x * 8;
#pragma unroll
  for (int rep = 0; rep < 2; rep++) {
    int idx = threadIdx.x + rep * 512;
    int r = idx >> 7;
    int q = idx & 127;
    *(float4*)(&prow[r][q * 4]) =
        *(const float4*)(pooled + (size_t)(g0 + r) * 512 + q * 4);
  }
  __syncthreads();
  float acc[8];
#pragma unroll
  for (int r = 0; r < 8; r++) acc[r] = 0.f;
  for (int k = 0; k < 512; k++) {
    float w = W[(size_t)k * 512 + j];
#pragma unroll
    for (int r = 0; r < 8; r++) acc[r] = fmaf(prow[r][k], w, acc[r]);
  }
  float bj = b[j];
#pragma unroll
  for (int r = 0; r < 8; r++)
    out1[(size_t)(g0 + r) * 512 + j] = fmaxf(0.f, acc[r] + bj);
}

// ------------- readout lin2 + sigmoid ------------------------------------
__global__ void lin2_kernel(const float* __restrict__ out1,
                            const float* __restrict__ W,
                            const float* __restrict__ b,
                            float* __restrict__ out) {
  int g = blockIdx.x;
  int lane = threadIdx.x;  // 64
  float s = 0.f;
  for (int k = lane; k < 512; k += 64)
    s = fmaf(out1[(size_t)g * 512 + k], W[k], s);
#pragma unroll
  for (int off = 32; off > 0; off >>= 1) s += __shfl_down(s, off);
  if (lane == 0) {
    float h = s + b[0];
    out[g] = 1.0f / (1.0f + expf(-h));
    out[GNUM + g] = h;
  }
}

extern "C" void kernel_launch(void* const* d_in, const int* in_sizes, int n_in,
                              void* d_out, int out_size, void* d_ws,
                              size_t ws_size, hipStream_t stream) {
  const float* x = (const float*)d_in[0];
  const int* ei = (const int*)d_in[1];
  const int* batch = (const int*)d_in[2];
  const float* c1_W1 = (const float*)d_in[3];
  const float* c1_b1 = (const float*)d_in[4];
  const float* c1_g  = (const float*)d_in[5];
  const float* c1_be = (const float*)d_in[6];
  const float* c1_W2 = (const float*)d_in[7];
  const float* c1_b2 = (const float*)d_in[8];
  const float* c2_W1 = (const float*)d_in[9];
  const float* c2_b1 = (const float*)d_in[10];
  const float* c2_g  = (const float*)d_in[11];
  const float* c2_be = (const float*)d_in[12];
  const float* c2_W2 = (const float*)d_in[13];
  const float* c2_b2 = (const float*)d_in[14];
  const float* lin1_W = (const float*)d_in[15];
  const float* lin1_b = (const float*)d_in[16];
  const float* lin2_W = (const float*)d_in[17];
  const float* lin2_b = (const float*)d_in[18];

  const int n = in_sizes[0] / D;        // 50000
  const int nE = in_sizes[1] / 2;       // 600000

  char* p = (char*)d_ws;
  auto take = [&](size_t bytes) {
    char* r = p;
    p += (bytes + 255) & ~(size_t)255;
    return r;
  };
  float* hpre   = (float*)take((size_t)n * D * 4);       // f32 gemm1/3 out
  f16*   aggt   = (f16*)take((size_t)n * D * 2);         // agg out / gemm A
  f16*   h1     = (f16*)take((size_t)n * D * 2);         // x16 then h1
  f16*   wt     = (f16*)take(4 * 16384 * 2);             // 4x W_T f16
  float* pooled = (float*)take((size_t)GNUM * 512 * 4);
  float* out1b  = (float*)take((size_t)GNUM * 512 * 4);
  float* colsum = (float*)take(256 * 4);
  int* deg      = (int*)take((size_t)n * 4);
  int* rowptr   = (int*)take((size_t)(n + 1) * 4);
  int* cursor   = (int*)take((size_t)(n + 1) * 4);
  int* partials = (int*)take(128 * 4);
  int* csr      = (int*)take((size_t)nE * 4);

  const int gemm_grid = (n + 127) / 128;    // 391
  const int edge_grid = (nE + 255) / 256;
  const int agg_grid = (n + 15) / 16;
  const int nP = (n + 511) / 512;           // 98
  const int n4 = n * D / 4;

  // ---------------- prep: CSR + W_T + x->f16 ----------------
  hipMemsetAsync(deg, 0, (size_t)n * sizeof(int), stream);
  hipMemsetAsync(pooled, 0, (size_t)GNUM * 512 * sizeof(float), stream);
  deg_kernel<<<edge_grid, 256, 0, stream>>>(ei, deg, nE);
  partial_kernel<<<nP, 256, 0, stream>>>(deg, partials, n);
  scanp_kernel<<<1, 128, 0, stream>>>(partials, nP, rowptr, n, nE);
  emit_kernel<<<nP, 256, 0, stream>>>(deg, partials, rowptr, cursor, n);
  fill_kernel<<<edge_grid, 256, 0, stream>>>(ei, cursor, csr, nE);
  wprep_kernel<<<256, 256, 0, stream>>>(c1_W1, c1_W2, c2_W1, c2_W2, wt);
  xcvt_kernel<<<(n4 + 255) / 256, 256, 0, stream>>>(x, h1, n4);  // x16 in h1

  // ---------------- layer 1 ----------------
  agg16_kernel<<<agg_grid, 256, 0, stream>>>(h1, rowptr, csr, aggt, n);
  gemm16_kernel<1, 0><<<gemm_grid, 256, 0, stream>>>(
      aggt, nullptr, wt, c1_b1, hpre, nullptr, nullptr, 0, n);
  hipMemsetAsync(colsum, 0, 256 * sizeof(float), stream);
  colreduce_kernel<<<256, 128, 0, stream>>>(hpre, colsum, n);
  bnstats_kernel<<<1, 128, 0, stream>>>(colsum, c1_g, c1_be, colsum, n);
  gemm16_kernel<0, 1><<<gemm_grid, 256, 0, stream>>>(
      hpre, colsum, wt + 16384, c1_b2, h1, batch, pooled, 0, n);

  // ---------------- layer 2 ----------------
  agg16_kernel<<<agg_grid, 256, 0, stream>>>(h1, rowptr, csr, aggt, n);
  gemm16_kernel<1, 0><<<gemm_grid, 256, 0, stream>>>(
      aggt, nullptr, wt + 32768, c2_b1, hpre, nullptr, nullptr, 0, n);
  hipMemsetAsync(colsum, 0, 256 * sizeof(float), stream);
  colreduce_kernel<<<256, 128, 0, stream>>>(hpre, colsum, n);
  bnstats_kernel<<<1, 128, 0, stream>>>(colsum, c2_g, c2_be, colsum, n);
  gemm16_kernel<0, 2><<<gemm_grid, 256, 0, stream>>>(
      hpre, colsum, wt + 49152, c2_b2, nullptr, batch, pooled, 128, n);

  // ---------------- readout ----------------
  lin1_kernel<<<GNUM / 8, 512, 0, stream>>>(pooled, lin1_W, lin1_b, out1b);
  lin2_kernel<<<GNUM, 64, 0, stream>>>(out1b, lin2_W, lin2_b, (float*)d_out);
}

// Round 6
// 279.169 us; speedup vs baseline: 3.3905x; 1.5963x over previous
//
#include <hip/hip_runtime.h>

#define D 128
#define GNUM 512

typedef _Float16 f16;
typedef _Float16 f16x8 __attribute__((ext_vector_type(8)));
typedef float f32x4 __attribute__((ext_vector_type(4)));

// ---------------- CSR build: degree histogram ----------------
__global__ void deg_kernel(const int* __restrict__ ei, int* __restrict__ deg,
                           int nE) {
  int e = blockIdx.x * blockDim.x + threadIdx.x;
  if (e < nE) atomicAdd(&deg[ei[nE + e]], 1);
}

// ------------- hierarchical scan: per-block partial sums ------------------
__global__ __launch_bounds__(256) void partial_kernel(
    const int* __restrict__ deg, int* __restrict__ partials, int n) {
  __shared__ int sh[256];
  const int t = threadIdx.x;
  const int i = blockIdx.x * 512 + t * 2;
  int s = 0;
  if (i < n) s += deg[i];
  if (i + 1 < n) s += deg[i + 1];
  sh[t] = s;
  __syncthreads();
#pragma unroll
  for (int off = 128; off > 0; off >>= 1) {
    if (t < off) sh[t] += sh[t + off];
    __syncthreads();
  }
  if (t == 0) partials[blockIdx.x] = sh[0];
}

// ------------- hierarchical scan: scan the partials (1 block) -------------
__global__ __launch_bounds__(128) void scanp_kernel(
    int* __restrict__ partials, int nP, int* __restrict__ rowptr, int n,
    int nE) {
  __shared__ int sh[128];
  const int t = threadIdx.x;
  const int v = (t < nP) ? partials[t] : 0;
  sh[t] = v;
  __syncthreads();
#pragma unroll
  for (int off = 1; off < 128; off <<= 1) {
    int u = (t >= off) ? sh[t - off] : 0;
    __syncthreads();
    sh[t] += u;
    __syncthreads();
  }
  if (t < nP) partials[t] = sh[t] - v;
  if (t == 0) rowptr[n] = nE;
}

// ------------- hierarchical scan: emit rowptr/cursor ----------------------
__global__ __launch_bounds__(256) void emit_kernel(
    const int* __restrict__ deg, const int* __restrict__ partials,
    int* __restrict__ rowptr, int* __restrict__ cursor, int n) {
  __shared__ int sh[256];
  const int t = threadIdx.x;
  const int i = blockIdx.x * 512 + t * 2;
  const int d0 = (i < n) ? deg[i] : 0;
  const int d1 = (i + 1 < n) ? deg[i + 1] : 0;
  const int s = d0 + d1;
  sh[t] = s;
  __syncthreads();
#pragma unroll
  for (int off = 1; off < 256; off <<= 1) {
    int u = (t >= off) ? sh[t - off] : 0;
    __syncthreads();
    sh[t] += u;
    __syncthreads();
  }
  int base = partials[blockIdx.x] + sh[t] - s;
  if (i < n) {
    rowptr[i] = base;
    cursor[i] = base;
    base += d0;
  }
  if (i + 1 < n) {
    rowptr[i + 1] = base;
    cursor[i + 1] = base;
  }
}

// ---------------- CSR build: fill src lists ----------------
__global__ void fill_kernel(const int* __restrict__ ei, int* __restrict__ cursor,
                            int* __restrict__ csr, int nE) {
  int e = blockIdx.x * blockDim.x + threadIdx.x;
  if (e < nE) {
    int d = ei[nE + e];
    int pos = atomicAdd(&cursor[d], 1);
    csr[pos] = ei[e];
  }
}

// ---------------- graph start offsets (batch is sorted) -------------------
__global__ void gstart_kernel(const int* __restrict__ batch,
                              int* __restrict__ gstart, int n) {
  int g = blockIdx.x * blockDim.x + threadIdx.x;
  if (g > GNUM) return;
  if (g == GNUM) { gstart[g] = n; return; }
  int lo = 0, hi = n;
  while (lo < hi) {
    int mid = (lo + hi) >> 1;
    if (batch[mid] < g) lo = mid + 1; else hi = mid;
  }
  gstart[g] = lo;
}

// ---------------- fp32 -> f16 convert ----------------
__global__ void xcvt_kernel(const float* __restrict__ in, f16* __restrict__ out,
                            int n4) {
  int i = blockIdx.x * 256 + threadIdx.x;
  if (i < n4) {
    float4 v = ((const float4*)in)[i];
    union { f16 h[4]; uint2 u; } p;
    p.h[0] = (f16)v.x; p.h[1] = (f16)v.y; p.h[2] = (f16)v.z; p.h[3] = (f16)v.w;
    ((uint2*)out)[i] = p.u;
  }
}

// ---------------- weight prep: W_T[w][col][k] = (f16)W_w[k][col] ----------
__global__ void wprep_kernel(const float* __restrict__ W0,
                             const float* __restrict__ W1,
                             const float* __restrict__ W2,
                             const float* __restrict__ W3,
                             f16* __restrict__ out) {
  int idx = blockIdx.x * 256 + threadIdx.x;  // 65536 total
  int wsel = idx >> 14;
  int rem = idx & 16383;
  int col = rem >> 7, k = rem & 127;
  const float* W = (wsel == 0) ? W0 : (wsel == 1) ? W1 : (wsel == 2) ? W2 : W3;
  out[idx] = (f16)W[k * D + col];
}

// ------- pull aggregation (f16 in/out): out[r] = f[r] + sum f[N(r)] -------
__global__ __launch_bounds__(256) void agg16_kernel(
    const f16* __restrict__ feat, const int* __restrict__ rowptr,
    const int* __restrict__ csr, f16* __restrict__ out, int n) {
  int row = blockIdx.x * 16 + (threadIdx.x >> 4);
  int q = threadIdx.x & 15;
  if (row >= n) return;
  const int co = q * 8;
  float a[8];
  f16x8 v = *(const f16x8*)(feat + (size_t)row * D + co);
#pragma unroll
  for (int j = 0; j < 8; j++) a[j] = (float)v[j];
  int beg = rowptr[row], end = rowptr[row + 1];
  int i = beg;
  for (; i + 1 < end; i += 2) {
    int s0 = csr[i], s1 = csr[i + 1];
    f16x8 v0 = *(const f16x8*)(feat + (size_t)s0 * D + co);
    f16x8 v1 = *(const f16x8*)(feat + (size_t)s1 * D + co);
#pragma unroll
    for (int j = 0; j < 8; j++) a[j] += (float)v0[j] + (float)v1[j];
  }
  if (i < end) {
    f16x8 v0 = *(const f16x8*)(feat + (size_t)csr[i] * D + co);
#pragma unroll
    for (int j = 0; j < 8; j++) a[j] += (float)v0[j];
  }
  f16x8 o;
#pragma unroll
  for (int j = 0; j < 8; j++) o[j] = (f16)a[j];
  *(f16x8*)(out + (size_t)row * D + co) = o;
}

// ---------------- MFMA GEMM: C[n,128] = f(A)[n,128] @ W[128,128] + b ------
// BN 0: f(A)=A (f16).  BN 1: f(A)=relu(A*ss[k]+ss[128+k]) (f16 in).
// OUT 0: C = A@W + b, store f16, fused col sum/sumsq -> pstat[block][256].
// OUT 1: relu(A@W + b), store f16.
// Block = 1 wave (64 thr), owns 32 rows x 128 cols.
template <int BN, int OUT>
__global__ __launch_bounds__(64) void gemm16_kernel(
    const f16* __restrict__ A, const float* __restrict__ ss,
    const f16* __restrict__ WT, const float* __restrict__ bias,
    f16* __restrict__ C, float* __restrict__ pstat, int n) {
  const int l = threadIdx.x;
  const int rw0 = blockIdx.x * 32;
  const int lr = l & 15;
  const int lq = l >> 4;
  const int lk = lq * 8;

  f32x4 acc[2][8];
#pragma unroll
  for (int m = 0; m < 2; m++)
#pragma unroll
    for (int nt = 0; nt < 8; nt++) acc[m][nt] = (f32x4)0.f;

#pragma unroll
  for (int s = 0; s < 4; s++) {
    const int k = s * 32 + lk;
    f16x8 af[2];
#pragma unroll
    for (int m = 0; m < 2; m++) {
      int row = rw0 + m * 16 + lr;
      f16x8 v = (f16x8)(f16)0.f;
      if (row < n) v = *(const f16x8*)(A + (size_t)row * D + k);
      if (BN) {
        float4 c0 = *(const float4*)(ss + k);
        float4 c1 = *(const float4*)(ss + k + 4);
        float4 h0 = *(const float4*)(ss + 128 + k);
        float4 h1 = *(const float4*)(ss + 128 + k + 4);
        f16x8 r;
        r[0] = (f16)fmaxf(0.f, fmaf((float)v[0], c0.x, h0.x));
        r[1] = (f16)fmaxf(0.f, fmaf((float)v[1], c0.y, h0.y));
        r[2] = (f16)fmaxf(0.f, fmaf((float)v[2], c0.z, h0.z));
        r[3] = (f16)fmaxf(0.f, fmaf((float)v[3], c0.w, h0.w));
        r[4] = (f16)fmaxf(0.f, fmaf((float)v[4], c1.x, h1.x));
        r[5] = (f16)fmaxf(0.f, fmaf((float)v[5], c1.y, h1.y));
        r[6] = (f16)fmaxf(0.f, fmaf((float)v[6], c1.z, h1.z));
        r[7] = (f16)fmaxf(0.f, fmaf((float)v[7], c1.w, h1.w));
        af[m] = r;
      } else {
        af[m] = v;
      }
    }
    f16x8 bf[8];
#pragma unroll
    for (int nt = 0; nt < 8; nt++) {
      int col = nt * 16 + lr;
      bf[nt] = *(const f16x8*)(WT + (size_t)col * D + k);
    }
#pragma unroll
    for (int m = 0; m < 2; m++)
#pragma unroll
      for (int nt = 0; nt < 8; nt++)
        acc[m][nt] = __builtin_amdgcn_mfma_f32_16x16x32_f16(af[m], bf[nt],
                                                            acc[m][nt], 0, 0, 0);
  }

  // ---------------- epilogue ----------------
  if constexpr (OUT == 0) {
    float ts[8], tq[8];
#pragma unroll
    for (int nt = 0; nt < 8; nt++) { ts[nt] = 0.f; tq[nt] = 0.f; }
#pragma unroll
    for (int m = 0; m < 2; m++)
#pragma unroll
      for (int r = 0; r < 4; r++) {
        int row = rw0 + m * 16 + lq * 4 + r;
        if (row < n) {
#pragma unroll
          for (int nt = 0; nt < 8; nt++) {
            float v = acc[m][nt][r] + bias[nt * 16 + lr];
            C[(size_t)row * D + nt * 16 + lr] = (f16)v;
            ts[nt] += v;
            tq[nt] = fmaf(v, v, tq[nt]);
          }
        }
      }
#pragma unroll
    for (int nt = 0; nt < 8; nt++) {
      ts[nt] += __shfl_xor(ts[nt], 16); ts[nt] += __shfl_xor(ts[nt], 32);
      tq[nt] += __shfl_xor(tq[nt], 16); tq[nt] += __shfl_xor(tq[nt], 32);
    }
    if (l < 16) {
      float* ps = pstat + (size_t)blockIdx.x * 256;
#pragma unroll
      for (int nt = 0; nt < 8; nt++) {
        ps[nt * 16 + l] = ts[nt];
        ps[128 + nt * 16 + l] = tq[nt];
      }
    }
  } else {
#pragma unroll
    for (int m = 0; m < 2; m++)
#pragma unroll
      for (int r = 0; r < 4; r++) {
        int row = rw0 + m * 16 + lq * 4 + r;
        if (row < n) {
#pragma unroll
          for (int nt = 0; nt < 8; nt++) {
            float v = fmaxf(0.f, acc[m][nt][r] + bias[nt * 16 + lr]);
            C[(size_t)row * D + nt * 16 + lr] = (f16)v;
          }
        }
      }
  }
}

// ------------- reduce per-block stats into colsum[256] --------------------
__global__ __launch_bounds__(256) void statreduce_kernel(
    const float* __restrict__ pstat, float* __restrict__ colsum, int nB) {
  int c = threadIdx.x;
  float s = 0.f;
  for (int b = blockIdx.x; b < nB; b += gridDim.x)
    s += pstat[(size_t)b * 256 + c];
  atomicAdd(colsum + c, s);
}

// ------------- BN stats -> scale/shift (in place on colsum) ---------------
__global__ void bnstats_kernel(const float* __restrict__ colsum,
                               const float* __restrict__ g,
                               const float* __restrict__ be,
                               float* __restrict__ ss, int n) {
  int c = threadIdx.x;  // 128
  float inv_n = 1.0f / (float)n;
  float mean = colsum[c] * inv_n;
  float var = colsum[128 + c] * inv_n - mean * mean;
  float scale = g[c] * rsqrtf(var + 1e-5f);
  ss[c] = scale;
  ss[128 + c] = be[c] - mean * scale;
}

// ------------- pooling: one block per graph, no atomics -------------------
__global__ __launch_bounds__(256) void pool2_kernel(
    const f16* __restrict__ h1, const f16* __restrict__ h2,
    const int* __restrict__ gstart, float* __restrict__ pooled) {
  int g = blockIdx.x;
  int c = threadIdx.x & 127;
  int half = threadIdx.x >> 7;
  int r0 = gstart[g], r1 = gstart[g + 1];
  float s1 = 0.f, m1 = 0.f, s2 = 0.f, m2 = 0.f;
  for (int r = r0 + half; r < r1; r += 2) {
    float v1 = (float)h1[(size_t)r * D + c];
    float v2 = (float)h2[(size_t)r * D + c];
    s1 += v1; m1 = fmaxf(m1, v1);
    s2 += v2; m2 = fmaxf(m2, v2);
  }
  __shared__ float sh[256];
  sh[threadIdx.x] = s1; __syncthreads();
  if (half == 0) s1 += sh[threadIdx.x + 128];
  __syncthreads(); sh[threadIdx.x] = s2; __syncthreads();
  if (half == 0) s2 += sh[threadIdx.x + 128];
  __syncthreads(); sh[threadIdx.x] = m1; __syncthreads();
  if (half == 0) m1 = fmaxf(m1, sh[threadIdx.x + 128]);
  __syncthreads(); sh[threadIdx.x] = m2; __syncthreads();
  if (half == 0) {
    m2 = fmaxf(m2, sh[threadIdx.x + 128]);
    float* pg = pooled + (size_t)g * 512;
    pg[c] = s1;
    pg[128 + c] = s2;
    pg[256 + c] = m1;
    pg[384 + c] = m2;
  }
}

// ------------- readout lin1: out1 += pooled[:,k-chunk] @ W[k-chunk,:] -----
// grid = 128 g-tiles x 4 k-chunks; bias/relu applied in lin2.
__global__ __launch_bounds__(512) void lin1_kernel(
    const float* __restrict__ pooled, const float* __restrict__ W,
    float* __restrict__ out1) {
  __shared__ float prow[4][128];
  const int j = threadIdx.x;
  const int gt = blockIdx.x >> 2;
  const int kt = blockIdx.x & 3;
  const int g0 = gt * 4, k0 = kt * 128;
  prow[j >> 7][j & 127] = pooled[(size_t)(g0 + (j >> 7)) * 512 + k0 + (j & 127)];
  __syncthreads();
  float acc[4] = {0.f, 0.f, 0.f, 0.f};
  for (int k = 0; k < 128; k++) {
    float w = W[(size_t)(k0 + k) * 512 + j];
#pragma unroll
    for (int r = 0; r < 4; r++) acc[r] = fmaf(prow[r][k], w, acc[r]);
  }
#pragma unroll
  for (int r = 0; r < 4; r++)
    atomicAdd(out1 + (size_t)(g0 + r) * 512 + j, acc[r]);
}

// ------------- readout lin2 (bias+relu of lin1 fused) + sigmoid -----------
__global__ void lin2_kernel(const float* __restrict__ out1,
                            const float* __restrict__ b1,
                            const float* __restrict__ W,
                            const float* __restrict__ b2,
                            float* __restrict__ out) {
  int g = blockIdx.x;
  int lane = threadIdx.x;  // 64
  float s = 0.f;
  for (int k = lane; k < 512; k += 64)
    s = fmaf(fmaxf(0.f, out1[(size_t)g * 512 + k] + b1[k]), W[k], s);
#pragma unroll
  for (int off = 32; off > 0; off >>= 1) s += __shfl_down(s, off);
  if (lane == 0) {
    float h = s + b2[0];
    out[g] = 1.0f / (1.0f + expf(-h));
    out[GNUM + g] = h;
  }
}

extern "C" void kernel_launch(void* const* d_in, const int* in_sizes, int n_in,
                              void* d_out, int out_size, void* d_ws,
                              size_t ws_size, hipStream_t stream) {
  const float* x = (const float*)d_in[0];
  const int* ei = (const int*)d_in[1];
  const int* batch = (const int*)d_in[2];
  const float* c1_W1 = (const float*)d_in[3];
  const float* c1_b1 = (const float*)d_in[4];
  const float* c1_g  = (const float*)d_in[5];
  const float* c1_be = (const float*)d_in[6];
  const float* c1_W2 = (const float*)d_in[7];
  const float* c1_b2 = (const float*)d_in[8];
  const float* c2_W1 = (const float*)d_in[9];
  const float* c2_b1 = (const float*)d_in[10];
  const float* c2_g  = (const float*)d_in[11];
  const float* c2_be = (const float*)d_in[12];
  const float* c2_W2 = (const float*)d_in[13];
  const float* c2_b2 = (const float*)d_in[14];
  const float* lin1_W = (const float*)d_in[15];
  const float* lin1_b = (const float*)d_in[16];
  const float* lin2_W = (const float*)d_in[17];
  const float* lin2_b = (const float*)d_in[18];

  const int n = in_sizes[0] / D;        // 50000
  const int nE = in_sizes[1] / 2;       // 600000

  char* p = (char*)d_ws;
  auto take = [&](size_t bytes) {
    char* r = p;
    p += (bytes + 255) & ~(size_t)255;
    return r;
  };
  f16*   hpre   = (f16*)take((size_t)n * D * 2);   // GEMM1 out (f16)
  f16*   aggt   = (f16*)take((size_t)n * D * 2);   // agg out, then h2
  f16*   h1     = (f16*)take((size_t)n * D * 2);   // x16, then h1
  f16*   wt     = (f16*)take(4 * 16384 * 2);       // 4x W_T f16
  float* pooled = (float*)take((size_t)GNUM * 512 * 4);
  float* out1b  = (float*)take((size_t)GNUM * 512 * 4);
  float* colsum = (float*)take(256 * 4);
  int*   gstart = (int*)take((GNUM + 1) * 4);
  int* deg      = (int*)take((size_t)n * 4);
  int* rowptr   = (int*)take((size_t)(n + 1) * 4);
  int* cursor   = (int*)take((size_t)(n + 1) * 4);
  int* partials = (int*)take(128 * 4);
  int* csr      = (int*)take((size_t)nE * 4);
  const int nB = (n + 31) / 32;                    // 1563 gemm blocks
  float* pstat  = (float*)take((size_t)nB * 256 * 4);

  const int edge_grid = (nE + 255) / 256;
  const int agg_grid = (n + 15) / 16;
  const int nP = (n + 511) / 512;
  const int n4 = n * D / 4;

  // ---------------- prep ----------------
  hipMemsetAsync(deg, 0, (size_t)n * sizeof(int), stream);
  hipMemsetAsync(out1b, 0, (size_t)GNUM * 512 * sizeof(float), stream);
  deg_kernel<<<edge_grid, 256, 0, stream>>>(ei, deg, nE);
  partial_kernel<<<nP, 256, 0, stream>>>(deg, partials, n);
  scanp_kernel<<<1, 128, 0, stream>>>(partials, nP, rowptr, n, nE);
  emit_kernel<<<nP, 256, 0, stream>>>(deg, partials, rowptr, cursor, n);
  fill_kernel<<<edge_grid, 256, 0, stream>>>(ei, cursor, csr, nE);
  gstart_kernel<<<3, 256, 0, stream>>>(batch, gstart, n);
  wprep_kernel<<<256, 256, 0, stream>>>(c1_W1, c1_W2, c2_W1, c2_W2, wt);
  xcvt_kernel<<<(n4 + 255) / 256, 256, 0, stream>>>(x, h1, n4);

  // ---------------- layer 1 ----------------
  agg16_kernel<<<agg_grid, 256, 0, stream>>>(h1, rowptr, csr, aggt, n);
  gemm16_kernel<0, 0><<<nB, 64, 0, stream>>>(aggt, nullptr, wt, c1_b1, hpre,
                                             pstat, n);
  hipMemsetAsync(colsum, 0, 256 * sizeof(float), stream);
  statreduce_kernel<<<32, 256, 0, stream>>>(pstat, colsum, nB);
  bnstats_kernel<<<1, 128, 0, stream>>>(colsum, c1_g, c1_be, colsum, n);
  gemm16_kernel<1, 1><<<nB, 64, 0, stream>>>(hpre, colsum, wt + 16384, c1_b2,
                                             h1, nullptr, n);

  // ---------------- layer 2 ----------------
  agg16_kernel<<<agg_grid, 256, 0, stream>>>(h1, rowptr, csr, aggt, n);
  gemm16_kernel<0, 0><<<nB, 64, 0, stream>>>(aggt, nullptr, wt + 32768, c2_b1,
                                             hpre, pstat, n);
  hipMemsetAsync(colsum, 0, 256 * sizeof(float), stream);
  statreduce_kernel<<<32, 256, 0, stream>>>(pstat, colsum, nB);
  bnstats_kernel<<<1, 128, 0, stream>>>(colsum, c2_g, c2_be, colsum, n);
  gemm16_kernel<1, 1><<<nB, 64, 0, stream>>>(hpre, colsum, wt + 49152, c2_b2,
                                             aggt, nullptr, n);  // h2 -> aggt

  // ---------------- pooling + readout ----------------
  pool2_kernel<<<GNUM, 256, 0, stream>>>(h1, aggt, gstart, pooled);
  lin1_kernel<<<512, 512, 0, stream>>>(pooled, lin1_W, out1b);
  lin2_kernel<<<GNUM, 64, 0, stream>>>(out1b, lin1_b, lin2_W, lin2_b,
                                       (float*)d_out);
}